// Round 16
// baseline (264.196 us; speedup 1.0000x reference)
//
#include <hip/hip_runtime.h>
#include <math.h>

#define DD 128          // node embedding dim
#define RR 1024         // root nodes
#define TT 4            // trunk types; encoder TT is the output autoencoder
#define LL 64           // levels
#define MM 2048         // nodes per level
#define NBK 16          // nodes per chunk (one MFMA M-tile)
#define GT 40           // chunk slots per trunk type
#define GO 14           // chunk slots for output type
#define CCAP (4*GT + GO)       // 174 global chunk slots per level == #WGs
#define PAD16 (CCAP*NBK)       // 2784 order slots per level
#define CH CCAP
#define NFLAGS (LL*CCAP*8)     // per (level, chunk, wave) flags

typedef __attribute__((ext_vector_type(8))) short short8v;   // 8 bf16 (4 VGPRs)
typedef __attribute__((ext_vector_type(4))) float f32x4;

static __device__ __forceinline__ unsigned short f2bf(float f) {
    unsigned u = __float_as_uint(f);
    unsigned r = (u + 0x7fffu + ((u >> 16) & 1u)) >> 16;   // RNE
    return (unsigned short)r;
}

// A&S 7.1.26 erf (|err| < 1.5e-7), branchless
static __device__ __forceinline__ float gelu_f(float h) {
    float x  = h * 0.70710678118654752f;
    float ax = fabsf(x);
    float t  = __builtin_amdgcn_rcpf(fmaf(0.3275911f, ax, 1.0f));
    float p  = fmaf(t, 1.061405429f, -1.453152027f);
    p = fmaf(p, t, 1.421413741f);
    p = fmaf(p, t, -0.284496736f);
    p = fmaf(p, t, 0.254829592f);
    p = p * t;
    float er = 1.0f - p * __expf(-ax * ax);
    er = copysignf(er, x);
    return 0.5f * h * (1.0f + er);
}

// ---------------------------------------------------------------------------
// Fused prep. 2-way sail/gate bucketing per fixed type region (r11/r13), with
// gate chunks HALF-FILLED (<=8 real nodes, 8 pad) when region capacity allows:
// halves the producer-set per gate chunk -> trims the max-over-producers tail.
// chunkof[node] = global chunk id. Flags per (level, chunk, wave).
// ---------------------------------------------------------------------------
__global__ __launch_bounds__(256) void prep_all(
    const float* __restrict__ root, const float* __restrict__ W1,
    const float* __restrict__ W2, const int* __restrict__ types,
    const int* __restrict__ par,
    float* __restrict__ buf,
    unsigned short* __restrict__ W1F, unsigned short* __restrict__ W2F,
    unsigned short* __restrict__ order, unsigned char* __restrict__ chunkof,
    unsigned int* __restrict__ flags)
{
    int bid = blockIdx.x, tid = threadIdx.x;
    if (bid < LL) {
        int l = bid;
        __shared__ int cnt[10], cur[10], gbase[5], g8[5];
        if (tid < 10) cnt[tid] = 0;
        __syncthreads();
        for (int s = tid; s < PAD16; s += 256) order[l*PAD16 + s] = 0xFFFFu;
        int thr = RR + (l-1)*MM;    // parents >= thr come from level l-1
        for (int m = tid; m < MM; m += 256) {
            int gi = l*MM + m;
            int t = types[gi];
            int e = (t >= TT) ? TT : t;
            int p0 = par[2*gi];
            bool rec = (p0 >= RR) && (p0 >= thr);
            if (t < TT) {
                int p1 = par[2*gi + 1];
                rec = rec || ((p1 >= RR) && (p1 >= thr));
            }
            atomicAdd(&cnt[e*2 + (rec ? 1 : 0)], 1);
        }
        __syncthreads();
        if (tid == 0) {
            for (int e = 0; e < 5; e++) {
                int G     = (e < 4) ? GT : GO;
                int base  = ((e < 4) ? e*GT : 4*GT) * NBK;
                int s = cnt[e*2], g = cnt[e*2 + 1];
                int sailch = (s + NBK - 1)/NBK;
                int gch8   = (g + 7)/8;
                int use8   = (sailch + gch8 <= G) ? 1 : 0;
                g8[e]    = use8;
                gbase[e] = base + sailch*NBK;
                cur[e*2]     = base;                       // sail: dense 16
                cur[e*2 + 1] = use8 ? 0 : gbase[e];        // gate: local idx if 8-cap
            }
        }
        __syncthreads();
        for (int m = tid; m < MM; m += 256) {
            int gi = l*MM + m;
            int t = types[gi];
            int e = (t >= TT) ? TT : t;
            int p0 = par[2*gi];
            bool rec = (p0 >= RR) && (p0 >= thr);
            if (t < TT) {
                int p1 = par[2*gi + 1];
                rec = rec || ((p1 >= RR) && (p1 >= thr));
            }
            int lin = atomicAdd(&cur[e*2 + (rec ? 1 : 0)], 1);
            int pos;
            if (rec && g8[e]) pos = gbase[e] + (lin >> 3)*NBK + (lin & 7);
            else              pos = lin;
            order[l*PAD16 + pos] = (unsigned short)m;
            chunkof[l*MM + m] = (unsigned char)(pos >> 4);   // global chunk id
        }
    } else if (bid < LL + 240) {
        int t0 = (bid - LL)*256 + tid;
        if (t0 < 5*16*8*64) {
            int lane = t0 & 63;
            int kk = (t0 >> 6) & 7;
            int nt = (t0 >> 9) & 15;
            int e  = t0 >> 13;
            int n  = nt*16 + (lane & 15);
            int k0 = kk*32 + (lane >> 4)*8;
            unsigned short v[8];
            #pragma unroll
            for (int j = 0; j < 8; j++) v[j] = f2bf(W1[(e*256 + k0 + j)*256 + n]);
            *(short8v*)&W1F[t0*8] = *(short8v*)v;
        } else {
            int t = t0 - 5*16*8*64;   // < 20480
            int lane = t & 63;
            int kk = (t >> 6) & 7;
            int nt = (t >> 9) & 7;
            int e  = t >> 12;
            int n  = nt*16 + (lane & 15);
            int k0 = kk*32 + (lane >> 4)*8;
            unsigned short v[8];
            #pragma unroll
            for (int j = 0; j < 8; j++) v[j] = f2bf(W2[(e*256 + k0 + j)*128 + n]);
            *(short8v*)&W2F[t*8] = *(short8v*)v;
        }
    } else if (bid < LL + 240 + 32) {
        int idx = (bid - (LL + 240))*256 + tid;   // 0..8191
        const f32x4* r4 = (const f32x4*)root;
        f32x4* o4 = (f32x4*)buf;
        #pragma unroll
        for (int q = 0; q < 4; q++) o4[idx*4 + q] = r4[idx*4 + q];
    } else {
        // zero per-wave flags (guarded)
        int idx = (bid - (LL + 240 + 32))*256 + tid;
        #pragma unroll
        for (int q = 0; q < 8; q++) {
            int fi = idx*8 + q;
            if (fi < NFLAGS) flags[fi] = 0u;
        }
    }
}

// ---------------------------------------------------------------------------
// Persistent dataflow kernel (r13 + fv3 late re-check): CCAP WGs x 512 threads.
// Static encoder type per WG; weights in VGPRs. Per-wave flags: producer wave
// w drains its own sc1 stores and publishes its own flag. Consumer thread
// (m, seg) depends on exactly one producer wave -> per-thread flag index.
// Flag checks: snapshot (1 level ahead) -> fresh re-load consumed mid-L1 ->
// fv3 re-load issued pre-stores (rides the drain) consumed post-publish ->
// phase-B spin only for the rest.
// ---------------------------------------------------------------------------
__global__ __launch_bounds__(512, 2) void persist_mfma(
    const unsigned short* __restrict__ W1F, const unsigned short* __restrict__ W2F,
    const float* __restrict__ b1, const float* __restrict__ b2,
    const float* __restrict__ slots, const int* __restrict__ par,
    const int* __restrict__ types, const unsigned short* __restrict__ order,
    const unsigned char* __restrict__ chunkof,
    float* __restrict__ buf, unsigned int* __restrict__ flags)
{
    __shared__ int4 descs[LL][NBK];            // {node, p0, p1(~slot if out), etype}
    __shared__ int2 descs2[LL][NBK];           // producer chunk id per parent (-1 ready)
    __shared__ int ech[LL];
    __shared__ unsigned short axFA[8*64*8];    // A-frags of x, 8 KB
    __shared__ unsigned short axFB[8*64*8];    // double buffer, 8 KB
    __shared__ unsigned short hxF[8*64*8];     // A-frags of h, 8 KB

    int tid = threadIdx.x;
    int wg  = blockIdx.x;
    int e_wg = (wg < 4*GT) ? (wg / GT) : TT;   // static encoder type of this WG

    int w  = tid >> 6;    // wave 0..7
    int lq = tid & 63;    // lane
    int m_own   = tid >> 4;   // gather row (tid<256)
    int seg_own = tid & 15;   // 16-float segment

    // ---- preload weight B-fragments + biases into registers ----
    short8v w1r0[8], w1r1[8], w2r[8];
    #pragma unroll
    for (int kk = 0; kk < 8; kk++) {
        w1r0[kk] = *(const short8v*)&W1F[(((e_wg*16 + 2*w + 0)*8 + kk)*64 + lq)*8];
        w1r1[kk] = *(const short8v*)&W1F[(((e_wg*16 + 2*w + 1)*8 + kk)*64 + lq)*8];
        w2r[kk]  = *(const short8v*)&W2F[(((e_wg*8  + w)*8 + kk)*64 + lq)*8];
    }
    float b1v0 = b1[e_wg*256 + (2*w + 0)*16 + (lq & 15)];
    float b1v1 = b1[e_wg*256 + (2*w + 1)*16 + (lq & 15)];
    float b2v  = b2[e_wg*128 + w*16 + (lq & 15)];

    // ---- prologue: resolve all levels' descriptors + producer chunk ids ----
    for (int i = tid; i < LL*NBK; i += 512) {
        int l = i >> 4, s = i & 15;
        unsigned short o = order[l*PAD16 + wg*NBK + s];
        int4 d; int2 d2 = make_int2(-1, -1);
        if (o == 0xFFFFu) {
            d = make_int4(-1, 0, 0, -1);
        } else {
            int gi = l*MM + (int)o;
            int t = types[gi];
            int e = (t >= TT) ? TT : t;
            int p0 = par[2*gi];
            int p1 = (t >= TT) ? ~(t - TT) : par[2*gi + 1];
            d = make_int4((int)o, p0, p1, e);
            if (p0 >= RR) d2.x = ((p0 - RR) >> 11)*CCAP + (int)chunkof[p0 - RR];
            if (p1 >= RR) d2.y = ((p1 - RR) >> 11)*CCAP + (int)chunkof[p1 - RR];
        }
        descs[l][s] = d;
        descs2[l][s] = d2;
    }
    __syncthreads();
    for (int i = tid; i < LL; i += 512) ech[i] = descs[i][0].w;
    __syncthreads();

    // resolve this thread's gather source + per-wave flag index for level l1
    #define RESOLVE(l1, S, F8, P) {                                            \
        int4 d_ = descs[l1][m_own];                                            \
        if (d_.x < 0) { P = true; S = nullptr; F8 = -1; }                      \
        else {                                                                 \
            P = false;                                                         \
            int2 d2_ = descs2[l1][m_own];                                      \
            if (seg_own < 8)  { S = buf + (size_t)d_.y*DD + seg_own*16;        \
                                F8 = (d2_.x >= 0) ? d2_.x*8 + seg_own : -1; }  \
            else if (d_.z < 0){ S = slots + (size_t)(~d_.z)*DD + (seg_own-8)*16; F8 = -1; } \
            else              { S = buf + (size_t)d_.z*DD + (seg_own-8)*16;    \
                                F8 = (d2_.y >= 0) ? d2_.y*8 + (seg_own-8) : -1; } \
        } }

    #define WRITE_FRAGS(AXT, V0, V1, V2, V3) {                                 \
        unsigned short tA_[8], tB_[8];                                         \
        _Pragma("unroll")                                                      \
        for (int j = 0; j < 4; j++) {                                          \
            tA_[j]   = f2bf(V0[j]); tA_[4+j] = f2bf(V1[j]);                    \
            tB_[j]   = f2bf(V2[j]); tB_[4+j] = f2bf(V3[j]);                    \
        }                                                                      \
        int k_ = seg_own*16;                                                   \
        int kk_ = k_ >> 5, ln_ = m_own + 16*((k_ >> 3) & 3);                   \
        *(short8v*)&AXT[(kk_*64 + ln_)*8] = *(short8v*)tA_;                    \
        k_ += 8; kk_ = k_ >> 5; ln_ = m_own + 16*((k_ >> 3) & 3);              \
        *(short8v*)&AXT[(kk_*64 + ln_)*8] = *(short8v*)tB_;                    \
    }

    // ---- level-0 gather (roots/slots: always ready) ----
    if (tid < 256) {
        const float* src; int f8; bool pad;
        RESOLVE(0, src, f8, pad);
        f32x4 z = (f32x4){0.f,0.f,0.f,0.f};
        f32x4 v0 = z, v1 = z, v2 = z, v3 = z;
        if (!pad) {
            const f32x4* s4 = (const f32x4*)src;
            v0 = s4[0]; v1 = s4[1]; v2 = s4[2]; v3 = s4[3];
        }
        WRITE_FRAGS(axFA, v0, v1, v2, v3);
    }
    // per-thread gather carry + flag snapshot for level 1
    const float* srcC = nullptr; int fiC = -1; bool padC = true; unsigned fvC = 1u;
    if (tid < 256) {
        RESOLVE(1, srcC, fiC, padC);
        if (!padC && fiC >= 0)
            fvC = __hip_atomic_load(&flags[fiC], __ATOMIC_RELAXED, __HIP_MEMORY_SCOPE_AGENT);
    }
    __syncthreads();

    unsigned short* axc = axFA;
    unsigned short* axn = axFB;

    for (int l = 0; l < LL; l++) {
        bool havN = (l + 1 < LL);

        // ---- phase A: row loads for snapshot-confirmed-ready parents ----
        bool pend = false; unsigned fv2 = 0u;
        f32x4 z = (f32x4){0.f,0.f,0.f,0.f};
        f32x4 v0 = z, v1 = z, v2 = z, v3 = z;
        if (havN && tid < 256 && !padC) {
            bool ready = (fiC < 0) || (fvC != 0u);
            if (ready) {
                asm volatile("" ::: "memory");
                const f32x4* s4 = (const f32x4*)srcC;
                v0 = s4[0]; v1 = s4[1]; v2 = s4[2]; v3 = s4[3];
            } else {
                pend = true;
                fv2 = __hip_atomic_load(&flags[fiC], __ATOMIC_RELAXED,
                                        __HIP_MEMORY_SCOPE_AGENT);
            }
        }
        __builtin_amdgcn_sched_barrier(0);   // pin: loads issued before compute

        int e = ech[l];
        unsigned fv3 = 0u;
        if (e >= 0) {
            // ---- layer 1: H = GELU(X @ W1 + b1), weights in VGPRs ----
            f32x4 acc0 = (f32x4){b1v0, b1v0, b1v0, b1v0};
            f32x4 acc1 = (f32x4){b1v1, b1v1, b1v1, b1v1};
            {
                const short8v* Ab = (const short8v*)axc;
                #pragma unroll
                for (int kk = 0; kk < 8; kk++) {
                    short8v a = Ab[kk*64 + lq];
                    acc0 = __builtin_amdgcn_mfma_f32_16x16x32_bf16(a, w1r0[kk], acc0, 0, 0, 0);
                    acc1 = __builtin_amdgcn_mfma_f32_16x16x32_bf16(a, w1r1[kk], acc1, 0, 0, 0);
                }
            }
            // ---- mid-check: late flag arrived? issue row loads now (hidden) ----
            if (pend && fv2 != 0u) {
                asm volatile("" ::: "memory");
                const f32x4* s4 = (const f32x4*)srcC;
                v0 = s4[0]; v1 = s4[1]; v2 = s4[2]; v3 = s4[3];
                pend = false;
            }
            __builtin_amdgcn_sched_barrier(0);

            // GELU + scatter H into A-frag LDS (nt = 2w+c, c in {0,1})
            #pragma unroll
            for (int c = 0; c < 2; c++) {
                int nh = (2*w + c)*16 + (lq & 15);
                int kk2 = nh >> 5;
                int jj  = nh & 7;
                int lhi = 16*((nh >> 3) & 3);
                #pragma unroll
                for (int r = 0; r < 4; r++) {
                    int m = (lq >> 4)*4 + r;
                    float h = (c == 0) ? acc0[r] : acc1[r];
                    hxF[(kk2*64 + (m + lhi))*8 + jj] = f2bf(gelu_f(h));
                }
            }
            __syncthreads();

            // ---- layer 2: OUT = H @ W2 + b2 (nt = w) ----
            f32x4 acc2 = (f32x4){b2v, b2v, b2v, b2v};
            {
                const short8v* Hb = (const short8v*)hxF;
                #pragma unroll
                for (int kk = 0; kk < 8; kk++) {
                    short8v a = Hb[kk*64 + lq];
                    acc2 = __builtin_amdgcn_mfma_f32_16x16x32_bf16(a, w2r[kk], acc2, 0, 0, 0);
                }
            }
            // ---- fv3: third flag re-check, issued pre-stores, rides the drain ----
            if (pend)
                fv3 = __hip_atomic_load(&flags[fiC], __ATOMIC_RELAXED,
                                        __HIP_MEMORY_SCOPE_AGENT);
            // result rows: sc1 write-through to the coherence point
            int baserow = RR + l*MM;
            int n = w*16 + (lq & 15);
            #pragma unroll
            for (int r = 0; r < 4; r++) {
                int m = (lq >> 4)*4 + r;
                int node = descs[l][m].x;
                if (node >= 0)
                    __hip_atomic_store(&buf[(size_t)(baserow + node)*DD + n], acc2[r],
                                       __ATOMIC_RELAXED, __HIP_MEMORY_SCOPE_AGENT);
            }
            // per-wave drain (vmcnt is per-wave) -> publish THIS WAVE's flag
            asm volatile("s_waitcnt vmcnt(0)" ::: "memory");
            if ((tid & 63) == 0)
                __hip_atomic_store(&flags[(l*CCAP + wg)*8 + w], 1u, __ATOMIC_RELAXED,
                                   __HIP_MEMORY_SCOPE_AGENT);
            // consume fv3: row loads issue here, ahead of phase-B observe leg
            if (pend && fv3 != 0u) {
                asm volatile("" ::: "memory");
                const f32x4* s4 = (const f32x4*)srcC;
                v0 = s4[0]; v1 = s4[1]; v2 = s4[2]; v3 = s4[3];
                pend = false;
            }
        }

        // ---- snapshot issue for level l+2 (per-thread; consumed at bottom) ----
        const float* srcN = nullptr; int fiN = -1; bool padN = true; unsigned fvN = 1u;
        if (l + 2 < LL && tid < 256) {
            RESOLVE(l+2, srcN, fiN, padN);
            if (!padN && fiN >= 0)
                fvN = __hip_atomic_load(&flags[fiN], __ATOMIC_RELAXED,
                                        __HIP_MEMORY_SCOPE_AGENT);
        }

        // ---- phase B: spin only on genuine still-pending parents ----
        if (havN && tid < 256) {
            if (pend) {
                while (__hip_atomic_load(&flags[fiC], __ATOMIC_RELAXED,
                                         __HIP_MEMORY_SCOPE_AGENT) == 0u)
                    __builtin_amdgcn_s_sleep(1);
                asm volatile("" ::: "memory");
                const f32x4* s4 = (const f32x4*)srcC;
                v0 = s4[0]; v1 = s4[1]; v2 = s4[2]; v3 = s4[3];
            }
            WRITE_FRAGS(axn, v0, v1, v2, v3);
        }

        __syncthreads();
        unsigned short* t2 = axc; axc = axn; axn = t2;
        srcC = srcN; fiC = fiN; padC = padN; fvC = fvN;
    }
}

extern "C" void kernel_launch(void* const* d_in, const int* in_sizes, int n_in,
                              void* d_out, int out_size, void* d_ws, size_t ws_size,
                              hipStream_t stream) {
    const float* root  = (const float*)d_in[0];   // (1024, 128)
    const float* W1    = (const float*)d_in[1];   // (5, 256, 256)
    const float* b1    = (const float*)d_in[2];   // (5, 256)
    const float* W2    = (const float*)d_in[3];   // (5, 256, 128)
    const float* b2    = (const float*)d_in[4];   // (5, 128)
    const float* slots = (const float*)d_in[5];   // (256, 128)
    const int*   par   = (const int*)d_in[6];     // (131072, 2)
    const int*   typ   = (const int*)d_in[7];     // (131072,)
    float* out = (float*)d_out;                   // (132096, 128)

    unsigned short* W1F     = (unsigned short*)d_ws;          // 327680 shorts
    unsigned short* W2F     = W1F + 5*16*8*64*8;              // 163840 shorts
    unsigned short* order   = W2F + 5*8*8*64*8;               // 64*2784 shorts
    unsigned char*  chunkof = (unsigned char*)(order + LL*PAD16);  // 131072 B
    unsigned int*   flags   = (unsigned int*)(chunkof + LL*MM);    // NFLAGS u32

    // single fused prep dispatch (order/chunkof, weights, roots, flags)
    prep_all<<<LL + 240 + 32 + 48, 256, 0, stream>>>(root, W1, W2, typ, par, out,
                                                     W1F, W2F, order, chunkof, flags);

    // persistent dataflow sweep (co-residency guaranteed by cooperative launch)
    void* args[] = { (void*)&W1F, (void*)&W2F, (void*)&b1, (void*)&b2,
                     (void*)&slots, (void*)&par, (void*)&typ, (void*)&order,
                     (void*)&chunkof, (void*)&out, (void*)&flags };
    hipLaunchCooperativeKernel((const void*)persist_mfma, dim3(CH), dim3(512),
                               args, 0, stream);
}

// Round 17
// 244.016 us; speedup vs baseline: 1.0827x; 1.0827x over previous
//
#include <hip/hip_runtime.h>
#include <math.h>

#define DD 128          // node embedding dim
#define RR 1024         // root nodes
#define TT 4            // trunk types; encoder TT is the output autoencoder
#define LL 64           // levels
#define MM 2048         // nodes per level
#define NBK 16          // nodes per chunk (one MFMA M-tile)
#define GT 37           // chunk slots per trunk type (cap 592 nodes, mean 486, 5.4σ)
#define GO 10           // chunk slots for output type (cap 160, mean 102, 5.8σ)
#define CCAP (4*GT + GO)       // 158 global chunk slots per level == #WGs
#define PAD16 (CCAP*NBK)       // 2528 order slots per level
#define CH CCAP
#define SENTU 0xFFFFFFFFu      // NaN sentinel; MLP outputs are finite -> never equal

typedef __attribute__((ext_vector_type(8))) short short8v;   // 8 bf16 (4 VGPRs)
typedef __attribute__((ext_vector_type(4))) float f32x4;

static __device__ __forceinline__ unsigned short f2bf(float f) {
    unsigned u = __float_as_uint(f);
    unsigned r = (u + 0x7fffu + ((u >> 16) & 1u)) >> 16;   // RNE
    return (unsigned short)r;
}

// A&S 7.1.26 erf (|err| < 1.5e-7), branchless
static __device__ __forceinline__ float gelu_f(float h) {
    float x  = h * 0.70710678118654752f;
    float ax = fabsf(x);
    float t  = __builtin_amdgcn_rcpf(fmaf(0.3275911f, ax, 1.0f));
    float p  = fmaf(t, 1.061405429f, -1.453152027f);
    p = fmaf(p, t, 1.421413741f);
    p = fmaf(p, t, -0.284496736f);
    p = fmaf(p, t, 0.254829592f);
    p = p * t;
    float er = 1.0f - p * __expf(-ax * ax);
    er = copysignf(er, x);
    return 0.5f * h * (1.0f + er);
}

// ---------------------------------------------------------------------------
// Fused prep: [0,64) order build (r13 2-way sail/gate, fixed type regions) |
// [64,304) weight convert | [304,336) root copy | [336,4432) SENTINEL fill of
// buf[RR..] (0xFFFFFFFF per dword). Dispatch-boundary flush publishes all of
// it before the persistent kernel starts.
// ---------------------------------------------------------------------------
__global__ __launch_bounds__(256) void prep_all(
    const float* __restrict__ root, const float* __restrict__ W1,
    const float* __restrict__ W2, const int* __restrict__ types,
    const int* __restrict__ par,
    float* __restrict__ buf,
    unsigned short* __restrict__ W1F, unsigned short* __restrict__ W2F,
    unsigned short* __restrict__ order)
{
    int bid = blockIdx.x, tid = threadIdx.x;
    if (bid < LL) {
        int l = bid;
        __shared__ int cnt[10], cur[10];
        if (tid < 10) cnt[tid] = 0;
        __syncthreads();
        for (int s = tid; s < PAD16; s += 256) order[l*PAD16 + s] = 0xFFFFu;
        int thr = RR + (l-1)*MM;    // parents >= thr come from level l-1
        for (int m = tid; m < MM; m += 256) {
            int gi = l*MM + m;
            int t = types[gi];
            int e = (t >= TT) ? TT : t;
            int p0 = par[2*gi];
            bool rec = (p0 >= RR) && (p0 >= thr);
            if (t < TT) {
                int p1 = par[2*gi + 1];
                rec = rec || ((p1 >= RR) && (p1 >= thr));
            }
            atomicAdd(&cnt[e*2 + (rec ? 1 : 0)], 1);
        }
        __syncthreads();
        if (tid == 0) {
            for (int e = 0; e < 5; e++) {
                int base = ((e < 4) ? e*GT : 4*GT) * NBK;
                int s = cnt[e*2];
                cur[e*2]     = base;
                cur[e*2 + 1] = base + ((s + NBK - 1)/NBK)*NBK;
            }
        }
        __syncthreads();
        for (int m = tid; m < MM; m += 256) {
            int gi = l*MM + m;
            int t = types[gi];
            int e = (t >= TT) ? TT : t;
            int p0 = par[2*gi];
            bool rec = (p0 >= RR) && (p0 >= thr);
            if (t < TT) {
                int p1 = par[2*gi + 1];
                rec = rec || ((p1 >= RR) && (p1 >= thr));
            }
            int pos = atomicAdd(&cur[e*2 + (rec ? 1 : 0)], 1);
            order[l*PAD16 + pos] = (unsigned short)m;
        }
    } else if (bid < LL + 240) {
        int t0 = (bid - LL)*256 + tid;
        if (t0 < 5*16*8*64) {
            int lane = t0 & 63;
            int kk = (t0 >> 6) & 7;
            int nt = (t0 >> 9) & 15;
            int e  = t0 >> 13;
            int n  = nt*16 + (lane & 15);
            int k0 = kk*32 + (lane >> 4)*8;
            unsigned short v[8];
            #pragma unroll
            for (int j = 0; j < 8; j++) v[j] = f2bf(W1[(e*256 + k0 + j)*256 + n]);
            *(short8v*)&W1F[t0*8] = *(short8v*)v;
        } else {
            int t = t0 - 5*16*8*64;   // < 20480
            int lane = t & 63;
            int kk = (t >> 6) & 7;
            int nt = (t >> 9) & 7;
            int e  = t >> 12;
            int n  = nt*16 + (lane & 15);
            int k0 = kk*32 + (lane >> 4)*8;
            unsigned short v[8];
            #pragma unroll
            for (int j = 0; j < 8; j++) v[j] = f2bf(W2[(e*256 + k0 + j)*128 + n]);
            *(short8v*)&W2F[t*8] = *(short8v*)v;
        }
    } else if (bid < LL + 240 + 32) {
        int idx = (bid - (LL + 240))*256 + tid;   // 0..8191
        const f32x4* r4 = (const f32x4*)root;
        f32x4* o4 = (f32x4*)buf;
        #pragma unroll
        for (int q = 0; q < 4; q++) o4[idx*4 + q] = r4[idx*4 + q];
    } else {
        // sentinel fill: rows RR..N-1, 16 floats per thread
        int idx = (bid - (LL + 240 + 32))*256 + tid;   // 0 .. 1048575
        float s = __uint_as_float(SENTU);
        f32x4 sv = (f32x4){s, s, s, s};
        f32x4* p = (f32x4*)(buf + (size_t)RR*DD) + (size_t)idx*4;
        p[0] = sv; p[1] = sv; p[2] = sv; p[3] = sv;
    }
}

// ---------------------------------------------------------------------------
// Persistent dataflow kernel: CCAP WGs x 512 threads (8 waves). Static encoder
// type per WG; weights in VGPRs (r12). NO FLAGS: consumers poll the parent
// row data itself (sc1 loads, sentinel-checked per dword); producers just
// fire sc1 stores -- no drain, no publish. Gather pipeline: issue loads in
// phase A -> verify mid-L1 (reissue if sentinel) -> verify post-stores ->
// phase-B spin only for genuine same-level parents.
// ---------------------------------------------------------------------------
__global__ __launch_bounds__(512, 2) void persist_mfma(
    const unsigned short* __restrict__ W1F, const unsigned short* __restrict__ W2F,
    const float* __restrict__ b1, const float* __restrict__ b2,
    const float* __restrict__ slots, const int* __restrict__ par,
    const int* __restrict__ types, const unsigned short* __restrict__ order,
    float* __restrict__ buf)
{
    __shared__ int4 descs[LL][NBK];            // {node, p0, p1(~slot if out), etype}
    __shared__ int ech[LL];
    __shared__ unsigned short axFA[8*64*8];    // A-frags of x, 8 KB
    __shared__ unsigned short axFB[8*64*8];    // double buffer, 8 KB
    __shared__ unsigned short hxF[8*64*8];     // A-frags of h, 8 KB

    int tid = threadIdx.x;
    int wg  = blockIdx.x;
    int e_wg = (wg < 4*GT) ? (wg / GT) : TT;   // static encoder type of this WG

    int w  = tid >> 6;    // wave 0..7
    int lq = tid & 63;    // lane
    int m_own   = tid >> 4;   // gather row (tid<256)
    int seg_own = tid & 15;   // 16-float segment

    // ---- preload weight B-fragments + biases into registers ----
    short8v w1r0[8], w1r1[8], w2r[8];
    #pragma unroll
    for (int kk = 0; kk < 8; kk++) {
        w1r0[kk] = *(const short8v*)&W1F[(((e_wg*16 + 2*w + 0)*8 + kk)*64 + lq)*8];
        w1r1[kk] = *(const short8v*)&W1F[(((e_wg*16 + 2*w + 1)*8 + kk)*64 + lq)*8];
        w2r[kk]  = *(const short8v*)&W2F[(((e_wg*8  + w)*8 + kk)*64 + lq)*8];
    }
    float b1v0 = b1[e_wg*256 + (2*w + 0)*16 + (lq & 15)];
    float b1v1 = b1[e_wg*256 + (2*w + 1)*16 + (lq & 15)];
    float b2v  = b2[e_wg*128 + w*16 + (lq & 15)];

    // ---- prologue: resolve all levels' descriptors ----
    for (int i = tid; i < LL*NBK; i += 512) {
        int l = i >> 4, s = i & 15;
        unsigned short o = order[l*PAD16 + wg*NBK + s];
        int4 d;
        if (o == 0xFFFFu) {
            d = make_int4(-1, 0, 0, -1);
        } else {
            int gi = l*MM + (int)o;
            int t = types[gi];
            int e = (t >= TT) ? TT : t;
            int p0 = par[2*gi];
            int p1 = (t >= TT) ? ~(t - TT) : par[2*gi + 1];
            d = make_int4((int)o, p0, p1, e);
        }
        descs[l][s] = d;
    }
    __syncthreads();
    for (int i = tid; i < LL; i += 512) ech[i] = descs[i][0].w;
    __syncthreads();

    // resolve this thread's gather source pointer for level l1
    #define RESOLVE_SRC(l1, S, P) {                                            \
        int4 d_ = descs[l1][m_own];                                            \
        if (d_.x < 0) { P = true; S = nullptr; }                               \
        else {                                                                 \
            P = false;                                                         \
            if (seg_own < 8)   S = buf + (size_t)d_.y*DD + seg_own*16;         \
            else if (d_.z < 0) S = slots + (size_t)(~d_.z)*DD + (seg_own-8)*16;\
            else               S = buf + (size_t)d_.z*DD + (seg_own-8)*16;     \
        } }

    #define LOAD8(S, U) {                                                      \
        const unsigned long long* s8_ = (const unsigned long long*)(S);        \
        _Pragma("unroll")                                                      \
        for (int q_ = 0; q_ < 8; q_++)                                         \
            U[q_] = __hip_atomic_load(&s8_[q_], __ATOMIC_RELAXED,              \
                                      __HIP_MEMORY_SCOPE_AGENT);               \
    }

    #define VERIFY(U, OK) { OK = true;                                         \
        _Pragma("unroll")                                                      \
        for (int q_ = 0; q_ < 8; q_++) {                                       \
            unsigned lo_ = (unsigned)U[q_], hi_ = (unsigned)(U[q_] >> 32);     \
            OK = OK && (lo_ != SENTU) && (hi_ != SENTU);                       \
        } }

    #define WRITE_FRAGS_U(AXT, U) {                                            \
        unsigned short tA_[8], tB_[8];                                         \
        _Pragma("unroll")                                                      \
        for (int q_ = 0; q_ < 4; q_++) {                                       \
            tA_[2*q_]   = f2bf(__uint_as_float((unsigned)U[q_]));              \
            tA_[2*q_+1] = f2bf(__uint_as_float((unsigned)(U[q_] >> 32)));      \
            tB_[2*q_]   = f2bf(__uint_as_float((unsigned)U[4+q_]));            \
            tB_[2*q_+1] = f2bf(__uint_as_float((unsigned)(U[4+q_] >> 32)));    \
        }                                                                      \
        int k_ = seg_own*16;                                                   \
        int kk_ = k_ >> 5, ln_ = m_own + 16*((k_ >> 3) & 3);                   \
        *(short8v*)&AXT[(kk_*64 + ln_)*8] = *(short8v*)tA_;                    \
        k_ += 8; kk_ = k_ >> 5; ln_ = m_own + 16*((k_ >> 3) & 3);              \
        *(short8v*)&AXT[(kk_*64 + ln_)*8] = *(short8v*)tB_;                    \
    }

    // ---- level-0 gather (roots/slots: data already clean) ----
    if (tid < 256) {
        const float* src; bool pad;
        RESOLVE_SRC(0, src, pad);
        unsigned long long u0[8];
        if (!pad) {
            LOAD8(src, u0);
            bool ok; VERIFY(u0, ok);
            while (!ok) { __builtin_amdgcn_s_sleep(1); LOAD8(src, u0); VERIFY(u0, ok); }
        } else {
            #pragma unroll
            for (int q = 0; q < 8; q++) u0[q] = 0ull;
        }
        WRITE_FRAGS_U(axFA, u0);
    }
    __syncthreads();

    unsigned short* axc = axFA;
    unsigned short* axn = axFB;

    for (int l = 0; l < LL; l++) {
        bool havN = (l + 1 < LL);

        // ---- phase A: issue sc1 data loads for level l+1 parents ----
        const float* srcN = nullptr; bool padN = true; bool ok = true;
        unsigned long long u[8];
        #pragma unroll
        for (int q = 0; q < 8; q++) u[q] = 0ull;
        if (havN && tid < 256) {
            RESOLVE_SRC(l+1, srcN, padN);
            if (!padN) { LOAD8(srcN, u); ok = false; }
        }
        __builtin_amdgcn_sched_barrier(0);   // pin: loads issued before compute

        int e = ech[l];
        if (e >= 0) {
            // ---- layer 1: H = GELU(X @ W1 + b1), weights in VGPRs ----
            f32x4 acc0 = (f32x4){b1v0, b1v0, b1v0, b1v0};
            f32x4 acc1 = (f32x4){b1v1, b1v1, b1v1, b1v1};
            {
                const short8v* Ab = (const short8v*)axc;
                #pragma unroll
                for (int kk = 0; kk < 8; kk++) {
                    short8v a = Ab[kk*64 + lq];
                    acc0 = __builtin_amdgcn_mfma_f32_16x16x32_bf16(a, w1r0[kk], acc0, 0, 0, 0);
                    acc1 = __builtin_amdgcn_mfma_f32_16x16x32_bf16(a, w1r1[kk], acc1, 0, 0, 0);
                }
            }
            // ---- check A: data arrived? if sentinel, reissue (hidden) ----
            if (havN && tid < 256 && !padN && !ok) {
                VERIFY(u, ok);
                if (!ok) LOAD8(srcN, u);
            }
            __builtin_amdgcn_sched_barrier(0);

            // GELU + scatter H into A-frag LDS (nt = 2w+c, c in {0,1})
            #pragma unroll
            for (int c = 0; c < 2; c++) {
                int nh = (2*w + c)*16 + (lq & 15);
                int kk2 = nh >> 5;
                int jj  = nh & 7;
                int lhi = 16*((nh >> 3) & 3);
                #pragma unroll
                for (int r = 0; r < 4; r++) {
                    int m = (lq >> 4)*4 + r;
                    float h = (c == 0) ? acc0[r] : acc1[r];
                    hxF[(kk2*64 + (m + lhi))*8 + jj] = f2bf(gelu_f(h));
                }
            }
            __syncthreads();

            // ---- layer 2: OUT = H @ W2 + b2 (nt = w) ----
            f32x4 acc2 = (f32x4){b2v, b2v, b2v, b2v};
            {
                const short8v* Hb = (const short8v*)hxF;
                #pragma unroll
                for (int kk = 0; kk < 8; kk++) {
                    short8v a = Hb[kk*64 + lq];
                    acc2 = __builtin_amdgcn_mfma_f32_16x16x32_bf16(a, w2r[kk], acc2, 0, 0, 0);
                }
            }
            // result rows: sc1 write-through; fire-and-forget (no drain, no flag)
            int baserow = RR + l*MM;
            int n = w*16 + (lq & 15);
            #pragma unroll
            for (int r = 0; r < 4; r++) {
                int m = (lq >> 4)*4 + r;
                int node = descs[l][m].x;
                if (node >= 0)
                    __hip_atomic_store(&buf[(size_t)(baserow + node)*DD + n], acc2[r],
                                       __ATOMIC_RELAXED, __HIP_MEMORY_SCOPE_AGENT);
            }
            // ---- check B: rides the store window ----
            if (havN && tid < 256 && !padN && !ok) {
                VERIFY(u, ok);
                if (!ok) LOAD8(srcN, u);
            }
        }

        // ---- phase B: spin only on genuine still-pending parents ----
        if (havN && tid < 256) {
            if (!padN) {
                while (!ok) {
                    VERIFY(u, ok);
                    if (!ok) { __builtin_amdgcn_s_sleep(1); LOAD8(srcN, u); }
                }
            }
            WRITE_FRAGS_U(axn, u);
        }

        __syncthreads();
        unsigned short* t2 = axc; axc = axn; axn = t2;
    }
}

extern "C" void kernel_launch(void* const* d_in, const int* in_sizes, int n_in,
                              void* d_out, int out_size, void* d_ws, size_t ws_size,
                              hipStream_t stream) {
    const float* root  = (const float*)d_in[0];   // (1024, 128)
    const float* W1    = (const float*)d_in[1];   // (5, 256, 256)
    const float* b1    = (const float*)d_in[2];   // (5, 256)
    const float* W2    = (const float*)d_in[3];   // (5, 256, 128)
    const float* b2    = (const float*)d_in[4];   // (5, 128)
    const float* slots = (const float*)d_in[5];   // (256, 128)
    const int*   par   = (const int*)d_in[6];     // (131072, 2)
    const int*   typ   = (const int*)d_in[7];     // (131072,)
    float* out = (float*)d_out;                   // (132096, 128)

    unsigned short* W1F   = (unsigned short*)d_ws;          // 327680 shorts
    unsigned short* W2F   = W1F + 5*16*8*64*8;              // 163840 shorts
    unsigned short* order = W2F + 5*8*8*64*8;               // 64*2528 shorts

    // single fused prep dispatch (order, weights, roots, SENTINEL fill)
    prep_all<<<LL + 240 + 32 + 4096, 256, 0, stream>>>(root, W1, W2, typ, par, out,
                                                       W1F, W2F, order);

    // persistent dataflow sweep (co-residency guaranteed by cooperative launch)
    void* args[] = { (void*)&W1F, (void*)&W2F, (void*)&b1, (void*)&b2,
                     (void*)&slots, (void*)&par, (void*)&typ, (void*)&order,
                     (void*)&out };
    hipLaunchCooperativeKernel((const void*)persist_mfma, dim3(CH), dim3(512),
                               args, 0, stream);
}

// Round 18
// 237.626 us; speedup vs baseline: 1.1118x; 1.0269x over previous
//
#include <hip/hip_runtime.h>
#include <math.h>

#define DD 128          // node embedding dim
#define RR 1024         // root nodes
#define TT 4            // trunk types; encoder TT is the output autoencoder
#define LL 64           // levels
#define MM 2048         // nodes per level
#define NBK 16          // nodes per chunk (one MFMA M-tile)
#define GT 56           // chunk slots per trunk type (room for 4-node gate chunks)
#define GO 14           // chunk slots for output type
#define CCAP (4*GT + GO)       // 238 global chunk slots per level == #WGs
#define PAD16 (CCAP*NBK)       // 3808 order slots per level
#define CH CCAP
#define SENTU 0xFFFFFFFFu      // NaN sentinel; MLP outputs are finite -> never equal

typedef __attribute__((ext_vector_type(8))) short short8v;   // 8 bf16 (4 VGPRs)
typedef __attribute__((ext_vector_type(4))) float f32x4;

static __device__ __forceinline__ unsigned short f2bf(float f) {
    unsigned u = __float_as_uint(f);
    unsigned r = (u + 0x7fffu + ((u >> 16) & 1u)) >> 16;   // RNE
    return (unsigned short)r;
}

// A&S 7.1.26 erf (|err| < 1.5e-7), branchless
static __device__ __forceinline__ float gelu_f(float h) {
    float x  = h * 0.70710678118654752f;
    float ax = fabsf(x);
    float t  = __builtin_amdgcn_rcpf(fmaf(0.3275911f, ax, 1.0f));
    float p  = fmaf(t, 1.061405429f, -1.453152027f);
    p = fmaf(p, t, 1.421413741f);
    p = fmaf(p, t, -0.284496736f);
    p = fmaf(p, t, 0.254829592f);
    p = p * t;
    float er = 1.0f - p * __expf(-ax * ax);
    er = copysignf(er, x);
    return 0.5f * h * (1.0f + er);
}

// ---------------------------------------------------------------------------
// Fused prep: [0,64) order build | [64,304) weight convert | [304,336) root
// copy | rest: SENTINEL fill of buf[RR..]. Gate chunks are packed at capacity
// gc in {4,8,16} nodes (smallest that fits the fixed type region): fewer
// producers per gate chunk -> thinner gate->gate critical chain + smaller
// max-over-producers tail. Sentinel polling needs no producer identity, so
// variable chunk sizes cost nothing on the consumer side.
// ---------------------------------------------------------------------------
__global__ __launch_bounds__(256) void prep_all(
    const float* __restrict__ root, const float* __restrict__ W1,
    const float* __restrict__ W2, const int* __restrict__ types,
    const int* __restrict__ par,
    float* __restrict__ buf,
    unsigned short* __restrict__ W1F, unsigned short* __restrict__ W2F,
    unsigned short* __restrict__ order)
{
    int bid = blockIdx.x, tid = threadIdx.x;
    if (bid < LL) {
        int l = bid;
        __shared__ int cnt[10], cur[10], gsh[5], gbase[5];
        if (tid < 10) cnt[tid] = 0;
        __syncthreads();
        for (int s = tid; s < PAD16; s += 256) order[l*PAD16 + s] = 0xFFFFu;
        int thr = RR + (l-1)*MM;    // parents >= thr come from level l-1
        for (int m = tid; m < MM; m += 256) {
            int gi = l*MM + m;
            int t = types[gi];
            int e = (t >= TT) ? TT : t;
            int p0 = par[2*gi];
            bool rec = (p0 >= RR) && (p0 >= thr);
            if (t < TT) {
                int p1 = par[2*gi + 1];
                rec = rec || ((p1 >= RR) && (p1 >= thr));
            }
            atomicAdd(&cnt[e*2 + (rec ? 1 : 0)], 1);
        }
        __syncthreads();
        if (tid == 0) {
            for (int e = 0; e < 5; e++) {
                int G    = (e < 4) ? GT : GO;
                int base = ((e < 4) ? e*GT : 4*GT) * NBK;
                int s = cnt[e*2], g = cnt[e*2 + 1];
                int sailch = (s + NBK - 1)/NBK;
                int sh;                         // gate capacity shift: 2->4, 3->8, 4->16
                if      (sailch + ((g + 3) >> 2) <= G) sh = 2;
                else if (sailch + ((g + 7) >> 3) <= G) sh = 3;
                else                                   sh = 4;
                gsh[e]   = sh;
                gbase[e] = base + sailch*NBK;
                cur[e*2]     = base;   // sail: dense 16, global slot index
                cur[e*2 + 1] = 0;      // gate: local linear index
            }
        }
        __syncthreads();
        for (int m = tid; m < MM; m += 256) {
            int gi = l*MM + m;
            int t = types[gi];
            int e = (t >= TT) ? TT : t;
            int p0 = par[2*gi];
            bool rec = (p0 >= RR) && (p0 >= thr);
            if (t < TT) {
                int p1 = par[2*gi + 1];
                rec = rec || ((p1 >= RR) && (p1 >= thr));
            }
            int lin = atomicAdd(&cur[e*2 + (rec ? 1 : 0)], 1);
            int pos;
            if (rec) {
                int sh = gsh[e];
                pos = gbase[e] + ((lin >> sh) << 4) + (lin & ((1 << sh) - 1));
            } else {
                pos = lin;
            }
            order[l*PAD16 + pos] = (unsigned short)m;
        }
    } else if (bid < LL + 240) {
        int t0 = (bid - LL)*256 + tid;
        if (t0 < 5*16*8*64) {
            int lane = t0 & 63;
            int kk = (t0 >> 6) & 7;
            int nt = (t0 >> 9) & 15;
            int e  = t0 >> 13;
            int n  = nt*16 + (lane & 15);
            int k0 = kk*32 + (lane >> 4)*8;
            unsigned short v[8];
            #pragma unroll
            for (int j = 0; j < 8; j++) v[j] = f2bf(W1[(e*256 + k0 + j)*256 + n]);
            *(short8v*)&W1F[t0*8] = *(short8v*)v;
        } else {
            int t = t0 - 5*16*8*64;   // < 20480
            int lane = t & 63;
            int kk = (t >> 6) & 7;
            int nt = (t >> 9) & 7;
            int e  = t >> 12;
            int n  = nt*16 + (lane & 15);
            int k0 = kk*32 + (lane >> 4)*8;
            unsigned short v[8];
            #pragma unroll
            for (int j = 0; j < 8; j++) v[j] = f2bf(W2[(e*256 + k0 + j)*128 + n]);
            *(short8v*)&W2F[t*8] = *(short8v*)v;
        }
    } else if (bid < LL + 240 + 32) {
        int idx = (bid - (LL + 240))*256 + tid;   // 0..8191
        const f32x4* r4 = (const f32x4*)root;
        f32x4* o4 = (f32x4*)buf;
        #pragma unroll
        for (int q = 0; q < 4; q++) o4[idx*4 + q] = r4[idx*4 + q];
    } else {
        // sentinel fill: rows RR..N-1, 16 floats per thread
        int idx = (bid - (LL + 240 + 32))*256 + tid;   // 0 .. 1048575
        float s = __uint_as_float(SENTU);
        f32x4 sv = (f32x4){s, s, s, s};
        f32x4* p = (f32x4*)(buf + (size_t)RR*DD) + (size_t)idx*4;
        p[0] = sv; p[1] = sv; p[2] = sv; p[3] = sv;
    }
}

// ---------------------------------------------------------------------------
// Persistent dataflow kernel (r17 verbatim): CCAP WGs x 512 threads (8 waves).
// Static encoder type per WG; weights in VGPRs. NO FLAGS: consumers poll the
// parent row data itself (sc1 loads, sentinel-checked per dword); producers
// just fire sc1 stores -- no drain, no publish. Gather pipeline: issue loads
// in phase A -> verify mid-L1 (reissue if sentinel) -> verify post-stores ->
// phase-B spin only for genuine same-level parents.
// ---------------------------------------------------------------------------
__global__ __launch_bounds__(512, 2) void persist_mfma(
    const unsigned short* __restrict__ W1F, const unsigned short* __restrict__ W2F,
    const float* __restrict__ b1, const float* __restrict__ b2,
    const float* __restrict__ slots, const int* __restrict__ par,
    const int* __restrict__ types, const unsigned short* __restrict__ order,
    float* __restrict__ buf)
{
    __shared__ int4 descs[LL][NBK];            // {node, p0, p1(~slot if out), etype}
    __shared__ int ech[LL];
    __shared__ unsigned short axFA[8*64*8];    // A-frags of x, 8 KB
    __shared__ unsigned short axFB[8*64*8];    // double buffer, 8 KB
    __shared__ unsigned short hxF[8*64*8];     // A-frags of h, 8 KB

    int tid = threadIdx.x;
    int wg  = blockIdx.x;
    int e_wg = (wg < 4*GT) ? (wg / GT) : TT;   // static encoder type of this WG

    int w  = tid >> 6;    // wave 0..7
    int lq = tid & 63;    // lane
    int m_own   = tid >> 4;   // gather row (tid<256)
    int seg_own = tid & 15;   // 16-float segment

    // ---- preload weight B-fragments + biases into registers ----
    short8v w1r0[8], w1r1[8], w2r[8];
    #pragma unroll
    for (int kk = 0; kk < 8; kk++) {
        w1r0[kk] = *(const short8v*)&W1F[(((e_wg*16 + 2*w + 0)*8 + kk)*64 + lq)*8];
        w1r1[kk] = *(const short8v*)&W1F[(((e_wg*16 + 2*w + 1)*8 + kk)*64 + lq)*8];
        w2r[kk]  = *(const short8v*)&W2F[(((e_wg*8  + w)*8 + kk)*64 + lq)*8];
    }
    float b1v0 = b1[e_wg*256 + (2*w + 0)*16 + (lq & 15)];
    float b1v1 = b1[e_wg*256 + (2*w + 1)*16 + (lq & 15)];
    float b2v  = b2[e_wg*128 + w*16 + (lq & 15)];

    // ---- prologue: resolve all levels' descriptors ----
    for (int i = tid; i < LL*NBK; i += 512) {
        int l = i >> 4, s = i & 15;
        unsigned short o = order[l*PAD16 + wg*NBK + s];
        int4 d;
        if (o == 0xFFFFu) {
            d = make_int4(-1, 0, 0, -1);
        } else {
            int gi = l*MM + (int)o;
            int t = types[gi];
            int e = (t >= TT) ? TT : t;
            int p0 = par[2*gi];
            int p1 = (t >= TT) ? ~(t - TT) : par[2*gi + 1];
            d = make_int4((int)o, p0, p1, e);
        }
        descs[l][s] = d;
    }
    __syncthreads();
    for (int i = tid; i < LL; i += 512) ech[i] = descs[i][0].w;
    __syncthreads();

    // resolve this thread's gather source pointer for level l1
    #define RESOLVE_SRC(l1, S, P) {                                            \
        int4 d_ = descs[l1][m_own];                                            \
        if (d_.x < 0) { P = true; S = nullptr; }                               \
        else {                                                                 \
            P = false;                                                         \
            if (seg_own < 8)   S = buf + (size_t)d_.y*DD + seg_own*16;         \
            else if (d_.z < 0) S = slots + (size_t)(~d_.z)*DD + (seg_own-8)*16;\
            else               S = buf + (size_t)d_.z*DD + (seg_own-8)*16;     \
        } }

    #define LOAD8(S, U) {                                                      \
        const unsigned long long* s8_ = (const unsigned long long*)(S);        \
        _Pragma("unroll")                                                      \
        for (int q_ = 0; q_ < 8; q_++)                                         \
            U[q_] = __hip_atomic_load(&s8_[q_], __ATOMIC_RELAXED,              \
                                      __HIP_MEMORY_SCOPE_AGENT);               \
    }

    #define VERIFY(U, OK) { OK = true;                                         \
        _Pragma("unroll")                                                      \
        for (int q_ = 0; q_ < 8; q_++) {                                       \
            unsigned lo_ = (unsigned)U[q_], hi_ = (unsigned)(U[q_] >> 32);     \
            OK = OK && (lo_ != SENTU) && (hi_ != SENTU);                       \
        } }

    #define WRITE_FRAGS_U(AXT, U) {                                            \
        unsigned short tA_[8], tB_[8];                                         \
        _Pragma("unroll")                                                      \
        for (int q_ = 0; q_ < 4; q_++) {                                       \
            tA_[2*q_]   = f2bf(__uint_as_float((unsigned)U[q_]));              \
            tA_[2*q_+1] = f2bf(__uint_as_float((unsigned)(U[q_] >> 32)));      \
            tB_[2*q_]   = f2bf(__uint_as_float((unsigned)U[4+q_]));            \
            tB_[2*q_+1] = f2bf(__uint_as_float((unsigned)(U[4+q_] >> 32)));    \
        }                                                                      \
        int k_ = seg_own*16;                                                   \
        int kk_ = k_ >> 5, ln_ = m_own + 16*((k_ >> 3) & 3);                   \
        *(short8v*)&AXT[(kk_*64 + ln_)*8] = *(short8v*)tA_;                    \
        k_ += 8; kk_ = k_ >> 5; ln_ = m_own + 16*((k_ >> 3) & 3);              \
        *(short8v*)&AXT[(kk_*64 + ln_)*8] = *(short8v*)tB_;                    \
    }

    // ---- level-0 gather (roots/slots: data already clean) ----
    if (tid < 256) {
        const float* src; bool pad;
        RESOLVE_SRC(0, src, pad);
        unsigned long long u0[8];
        if (!pad) {
            LOAD8(src, u0);
            bool ok; VERIFY(u0, ok);
            while (!ok) { __builtin_amdgcn_s_sleep(1); LOAD8(src, u0); VERIFY(u0, ok); }
        } else {
            #pragma unroll
            for (int q = 0; q < 8; q++) u0[q] = 0ull;
        }
        WRITE_FRAGS_U(axFA, u0);
    }
    __syncthreads();

    unsigned short* axc = axFA;
    unsigned short* axn = axFB;

    for (int l = 0; l < LL; l++) {
        bool havN = (l + 1 < LL);

        // ---- phase A: issue sc1 data loads for level l+1 parents ----
        const float* srcN = nullptr; bool padN = true; bool ok = true;
        unsigned long long u[8];
        #pragma unroll
        for (int q = 0; q < 8; q++) u[q] = 0ull;
        if (havN && tid < 256) {
            RESOLVE_SRC(l+1, srcN, padN);
            if (!padN) { LOAD8(srcN, u); ok = false; }
        }
        __builtin_amdgcn_sched_barrier(0);   // pin: loads issued before compute

        int e = ech[l];
        if (e >= 0) {
            // ---- layer 1: H = GELU(X @ W1 + b1), weights in VGPRs ----
            f32x4 acc0 = (f32x4){b1v0, b1v0, b1v0, b1v0};
            f32x4 acc1 = (f32x4){b1v1, b1v1, b1v1, b1v1};
            {
                const short8v* Ab = (const short8v*)axc;
                #pragma unroll
                for (int kk = 0; kk < 8; kk++) {
                    short8v a = Ab[kk*64 + lq];
                    acc0 = __builtin_amdgcn_mfma_f32_16x16x32_bf16(a, w1r0[kk], acc0, 0, 0, 0);
                    acc1 = __builtin_amdgcn_mfma_f32_16x16x32_bf16(a, w1r1[kk], acc1, 0, 0, 0);
                }
            }
            // ---- check A: data arrived? if sentinel, reissue (hidden) ----
            if (havN && tid < 256 && !padN && !ok) {
                VERIFY(u, ok);
                if (!ok) LOAD8(srcN, u);
            }
            __builtin_amdgcn_sched_barrier(0);

            // GELU + scatter H into A-frag LDS (nt = 2w+c, c in {0,1})
            #pragma unroll
            for (int c = 0; c < 2; c++) {
                int nh = (2*w + c)*16 + (lq & 15);
                int kk2 = nh >> 5;
                int jj  = nh & 7;
                int lhi = 16*((nh >> 3) & 3);
                #pragma unroll
                for (int r = 0; r < 4; r++) {
                    int m = (lq >> 4)*4 + r;
                    float h = (c == 0) ? acc0[r] : acc1[r];
                    hxF[(kk2*64 + (m + lhi))*8 + jj] = f2bf(gelu_f(h));
                }
            }
            __syncthreads();

            // ---- layer 2: OUT = H @ W2 + b2 (nt = w) ----
            f32x4 acc2 = (f32x4){b2v, b2v, b2v, b2v};
            {
                const short8v* Hb = (const short8v*)hxF;
                #pragma unroll
                for (int kk = 0; kk < 8; kk++) {
                    short8v a = Hb[kk*64 + lq];
                    acc2 = __builtin_amdgcn_mfma_f32_16x16x32_bf16(a, w2r[kk], acc2, 0, 0, 0);
                }
            }
            // result rows: sc1 write-through; fire-and-forget (no drain, no flag)
            int baserow = RR + l*MM;
            int n = w*16 + (lq & 15);
            #pragma unroll
            for (int r = 0; r < 4; r++) {
                int m = (lq >> 4)*4 + r;
                int node = descs[l][m].x;
                if (node >= 0)
                    __hip_atomic_store(&buf[(size_t)(baserow + node)*DD + n], acc2[r],
                                       __ATOMIC_RELAXED, __HIP_MEMORY_SCOPE_AGENT);
            }
            // ---- check B: rides the store window ----
            if (havN && tid < 256 && !padN && !ok) {
                VERIFY(u, ok);
                if (!ok) LOAD8(srcN, u);
            }
        }

        // ---- phase B: spin only on genuine still-pending parents ----
        if (havN && tid < 256) {
            if (!padN) {
                while (!ok) {
                    VERIFY(u, ok);
                    if (!ok) { __builtin_amdgcn_s_sleep(1); LOAD8(srcN, u); }
                }
            }
            WRITE_FRAGS_U(axn, u);
        }

        __syncthreads();
        unsigned short* t2 = axc; axc = axn; axn = t2;
    }
}

extern "C" void kernel_launch(void* const* d_in, const int* in_sizes, int n_in,
                              void* d_out, int out_size, void* d_ws, size_t ws_size,
                              hipStream_t stream) {
    const float* root  = (const float*)d_in[0];   // (1024, 128)
    const float* W1    = (const float*)d_in[1];   // (5, 256, 256)
    const float* b1    = (const float*)d_in[2];   // (5, 256)
    const float* W2    = (const float*)d_in[3];   // (5, 256, 128)
    const float* b2    = (const float*)d_in[4];   // (5, 128)
    const float* slots = (const float*)d_in[5];   // (256, 128)
    const int*   par   = (const int*)d_in[6];     // (131072, 2)
    const int*   typ   = (const int*)d_in[7];     // (131072,)
    float* out = (float*)d_out;                   // (132096, 128)

    unsigned short* W1F   = (unsigned short*)d_ws;          // 327680 shorts
    unsigned short* W2F   = W1F + 5*16*8*64*8;              // 163840 shorts
    unsigned short* order = W2F + 5*8*8*64*8;               // 64*3808 shorts

    // single fused prep dispatch (order, weights, roots, SENTINEL fill)
    prep_all<<<LL + 240 + 32 + 4096, 256, 0, stream>>>(root, W1, W2, typ, par, out,
                                                       W1F, W2F, order);

    // persistent dataflow sweep (co-residency guaranteed by cooperative launch)
    void* args[] = { (void*)&W1F, (void*)&W2F, (void*)&b1, (void*)&b2,
                     (void*)&slots, (void*)&par, (void*)&typ, (void*)&order,
                     (void*)&out };
    hipLaunchCooperativeKernel((const void*)persist_mfma, dim3(CH), dim3(512),
                               args, 0, stream);
}

// Round 19
// 222.715 us; speedup vs baseline: 1.1862x; 1.0670x over previous
//
#include <hip/hip_runtime.h>
#include <math.h>

#define DD 128          // node embedding dim
#define RR 1024         // root nodes
#define TT 4            // trunk types; encoder TT is the output autoencoder
#define LL 64           // levels
#define MM 2048         // nodes per level
#define NBK 16          // nodes per chunk (one MFMA M-tile)
#define GT 37           // chunk slots per trunk type (cap 592 nodes, mean 486, 5.4σ)
#define GO 10           // chunk slots for output type (cap 160, mean 102, 5.8σ)
#define CCAP (4*GT + GO)       // 158 global chunk slots per level == #WGs
#define PAD16 (CCAP*NBK)       // 2528 order slots per level
#define CH CCAP
#define SENTU 0xFFFFFFFFu      // NaN sentinel; MLP outputs are finite -> never equal

typedef __attribute__((ext_vector_type(8))) short short8v;   // 8 bf16 (4 VGPRs)
typedef __attribute__((ext_vector_type(4))) float f32x4;

static __device__ __forceinline__ unsigned short f2bf(float f) {
    unsigned u = __float_as_uint(f);
    unsigned r = (u + 0x7fffu + ((u >> 16) & 1u)) >> 16;   // RNE
    return (unsigned short)r;
}

// A&S 7.1.26 erf (|err| < 1.5e-7), branchless
static __device__ __forceinline__ float gelu_f(float h) {
    float x  = h * 0.70710678118654752f;
    float ax = fabsf(x);
    float t  = __builtin_amdgcn_rcpf(fmaf(0.3275911f, ax, 1.0f));
    float p  = fmaf(t, 1.061405429f, -1.453152027f);
    p = fmaf(p, t, 1.421413741f);
    p = fmaf(p, t, -0.284496736f);
    p = fmaf(p, t, 0.254829592f);
    p = p * t;
    float er = 1.0f - p * __expf(-ax * ax);
    er = copysignf(er, x);
    return 0.5f * h * (1.0f + er);
}

// ---------------------------------------------------------------------------
// Fused prep (r17): order build | weight convert | root copy | sentinel fill.
// ---------------------------------------------------------------------------
__global__ __launch_bounds__(256) void prep_all(
    const float* __restrict__ root, const float* __restrict__ W1,
    const float* __restrict__ W2, const int* __restrict__ types,
    const int* __restrict__ par,
    float* __restrict__ buf,
    unsigned short* __restrict__ W1F, unsigned short* __restrict__ W2F,
    unsigned short* __restrict__ order)
{
    int bid = blockIdx.x, tid = threadIdx.x;
    if (bid < LL) {
        int l = bid;
        __shared__ int cnt[10], cur[10];
        if (tid < 10) cnt[tid] = 0;
        __syncthreads();
        for (int s = tid; s < PAD16; s += 256) order[l*PAD16 + s] = 0xFFFFu;
        int thr = RR + (l-1)*MM;    // parents >= thr come from level l-1
        for (int m = tid; m < MM; m += 256) {
            int gi = l*MM + m;
            int t = types[gi];
            int e = (t >= TT) ? TT : t;
            int p0 = par[2*gi];
            bool rec = (p0 >= RR) && (p0 >= thr);
            if (t < TT) {
                int p1 = par[2*gi + 1];
                rec = rec || ((p1 >= RR) && (p1 >= thr));
            }
            atomicAdd(&cnt[e*2 + (rec ? 1 : 0)], 1);
        }
        __syncthreads();
        if (tid == 0) {
            for (int e = 0; e < 5; e++) {
                int base = ((e < 4) ? e*GT : 4*GT) * NBK;
                int s = cnt[e*2];
                cur[e*2]     = base;
                cur[e*2 + 1] = base + ((s + NBK - 1)/NBK)*NBK;
            }
        }
        __syncthreads();
        for (int m = tid; m < MM; m += 256) {
            int gi = l*MM + m;
            int t = types[gi];
            int e = (t >= TT) ? TT : t;
            int p0 = par[2*gi];
            bool rec = (p0 >= RR) && (p0 >= thr);
            if (t < TT) {
                int p1 = par[2*gi + 1];
                rec = rec || ((p1 >= RR) && (p1 >= thr));
            }
            int pos = atomicAdd(&cur[e*2 + (rec ? 1 : 0)], 1);
            order[l*PAD16 + pos] = (unsigned short)m;
        }
    } else if (bid < LL + 240) {
        int t0 = (bid - LL)*256 + tid;
        if (t0 < 5*16*8*64) {
            int lane = t0 & 63;
            int kk = (t0 >> 6) & 7;
            int nt = (t0 >> 9) & 15;
            int e  = t0 >> 13;
            int n  = nt*16 + (lane & 15);
            int k0 = kk*32 + (lane >> 4)*8;
            unsigned short v[8];
            #pragma unroll
            for (int j = 0; j < 8; j++) v[j] = f2bf(W1[(e*256 + k0 + j)*256 + n]);
            *(short8v*)&W1F[t0*8] = *(short8v*)v;
        } else {
            int t = t0 - 5*16*8*64;   // < 20480
            int lane = t & 63;
            int kk = (t >> 6) & 7;
            int nt = (t >> 9) & 7;
            int e  = t >> 12;
            int n  = nt*16 + (lane & 15);
            int k0 = kk*32 + (lane >> 4)*8;
            unsigned short v[8];
            #pragma unroll
            for (int j = 0; j < 8; j++) v[j] = f2bf(W2[(e*256 + k0 + j)*128 + n]);
            *(short8v*)&W2F[t*8] = *(short8v*)v;
        }
    } else if (bid < LL + 240 + 32) {
        int idx = (bid - (LL + 240))*256 + tid;   // 0..8191
        const f32x4* r4 = (const f32x4*)root;
        f32x4* o4 = (f32x4*)buf;
        #pragma unroll
        for (int q = 0; q < 4; q++) o4[idx*4 + q] = r4[idx*4 + q];
    } else {
        // sentinel fill: rows RR..N-1, 16 floats per thread
        int idx = (bid - (LL + 240 + 32))*256 + tid;   // 0 .. 1048575
        float s = __uint_as_float(SENTU);
        f32x4 sv = (f32x4){s, s, s, s};
        f32x4* p = (f32x4*)(buf + (size_t)RR*DD) + (size_t)idx*4;
        p[0] = sv; p[1] = sv; p[2] = sv; p[3] = sv;
    }
}

// ---------------------------------------------------------------------------
// Persistent dataflow kernel: CCAP WGs x 512 threads (8 waves). Static encoder
// type per WG; weights in VGPRs. Sentinel-poll protocol (r17), but phase-A
// gather loads are PLAIN CACHED: dispatch-start invalidated L2, and buf rows
// are only ever written via sc1 (L2-bypass), so a plain load returns either
// the real value or the sentinel -- never stale data. Sail parents (old) thus
// become L2 hits; only sentinel-misses fall back to sc1 reload/spin.
// Accumulator chains split 8 -> 4+4 to halve dependent-MFMA latency.
// ---------------------------------------------------------------------------
__global__ __launch_bounds__(512, 2) void persist_mfma(
    const unsigned short* __restrict__ W1F, const unsigned short* __restrict__ W2F,
    const float* __restrict__ b1, const float* __restrict__ b2,
    const float* __restrict__ slots, const int* __restrict__ par,
    const int* __restrict__ types, const unsigned short* __restrict__ order,
    float* __restrict__ buf)
{
    __shared__ int4 descs[LL][NBK];            // {node, p0, p1(~slot if out), etype}
    __shared__ int ech[LL];
    __shared__ unsigned short axFA[8*64*8];    // A-frags of x, 8 KB
    __shared__ unsigned short axFB[8*64*8];    // double buffer, 8 KB
    __shared__ unsigned short hxF[8*64*8];     // A-frags of h, 8 KB

    int tid = threadIdx.x;
    int wg  = blockIdx.x;
    int e_wg = (wg < 4*GT) ? (wg / GT) : TT;   // static encoder type of this WG

    int w  = tid >> 6;    // wave 0..7
    int lq = tid & 63;    // lane
    int m_own   = tid >> 4;   // gather row (tid<256)
    int seg_own = tid & 15;   // 16-float segment

    // ---- preload weight B-fragments + biases into registers ----
    short8v w1r0[8], w1r1[8], w2r[8];
    #pragma unroll
    for (int kk = 0; kk < 8; kk++) {
        w1r0[kk] = *(const short8v*)&W1F[(((e_wg*16 + 2*w + 0)*8 + kk)*64 + lq)*8];
        w1r1[kk] = *(const short8v*)&W1F[(((e_wg*16 + 2*w + 1)*8 + kk)*64 + lq)*8];
        w2r[kk]  = *(const short8v*)&W2F[(((e_wg*8  + w)*8 + kk)*64 + lq)*8];
    }
    float b1v0 = b1[e_wg*256 + (2*w + 0)*16 + (lq & 15)];
    float b1v1 = b1[e_wg*256 + (2*w + 1)*16 + (lq & 15)];
    float b2v  = b2[e_wg*128 + w*16 + (lq & 15)];

    // ---- prologue: resolve all levels' descriptors ----
    for (int i = tid; i < LL*NBK; i += 512) {
        int l = i >> 4, s = i & 15;
        unsigned short o = order[l*PAD16 + wg*NBK + s];
        int4 d;
        if (o == 0xFFFFu) {
            d = make_int4(-1, 0, 0, -1);
        } else {
            int gi = l*MM + (int)o;
            int t = types[gi];
            int e = (t >= TT) ? TT : t;
            int p0 = par[2*gi];
            int p1 = (t >= TT) ? ~(t - TT) : par[2*gi + 1];
            d = make_int4((int)o, p0, p1, e);
        }
        descs[l][s] = d;
    }
    __syncthreads();
    for (int i = tid; i < LL; i += 512) ech[i] = descs[i][0].w;
    __syncthreads();

    // resolve this thread's gather source pointer for level l1
    #define RESOLVE_SRC(l1, S, P) {                                            \
        int4 d_ = descs[l1][m_own];                                            \
        if (d_.x < 0) { P = true; S = nullptr; }                               \
        else {                                                                 \
            P = false;                                                         \
            if (seg_own < 8)   S = buf + (size_t)d_.y*DD + seg_own*16;         \
            else if (d_.z < 0) S = slots + (size_t)(~d_.z)*DD + (seg_own-8)*16;\
            else               S = buf + (size_t)d_.z*DD + (seg_own-8)*16;     \
        } }

    // plain cached loads (fast path; may return sentinel if not yet landed)
    #define LOAD8P(S, U) {                                                     \
        const unsigned long long* s8_ = (const unsigned long long*)(S);        \
        _Pragma("unroll")                                                      \
        for (int q_ = 0; q_ < 8; q_++) U[q_] = s8_[q_];                        \
    }

    // sc1 L2-bypass loads (truth path for pending parents)
    #define LOAD8(S, U) {                                                      \
        const unsigned long long* s8_ = (const unsigned long long*)(S);        \
        _Pragma("unroll")                                                      \
        for (int q_ = 0; q_ < 8; q_++)                                         \
            U[q_] = __hip_atomic_load(&s8_[q_], __ATOMIC_RELAXED,              \
                                      __HIP_MEMORY_SCOPE_AGENT);               \
    }

    #define VERIFY(U, OK) { OK = true;                                         \
        _Pragma("unroll")                                                      \
        for (int q_ = 0; q_ < 8; q_++) {                                       \
            unsigned lo_ = (unsigned)U[q_], hi_ = (unsigned)(U[q_] >> 32);     \
            OK = OK && (lo_ != SENTU) && (hi_ != SENTU);                       \
        } }

    #define WRITE_FRAGS_U(AXT, U) {                                            \
        unsigned short tA_[8], tB_[8];                                         \
        _Pragma("unroll")                                                      \
        for (int q_ = 0; q_ < 4; q_++) {                                       \
            tA_[2*q_]   = f2bf(__uint_as_float((unsigned)U[q_]));              \
            tA_[2*q_+1] = f2bf(__uint_as_float((unsigned)(U[q_] >> 32)));      \
            tB_[2*q_]   = f2bf(__uint_as_float((unsigned)U[4+q_]));            \
            tB_[2*q_+1] = f2bf(__uint_as_float((unsigned)(U[4+q_] >> 32)));    \
        }                                                                      \
        int k_ = seg_own*16;                                                   \
        int kk_ = k_ >> 5, ln_ = m_own + 16*((k_ >> 3) & 3);                   \
        *(short8v*)&AXT[(kk_*64 + ln_)*8] = *(short8v*)tA_;                    \
        k_ += 8; kk_ = k_ >> 5; ln_ = m_own + 16*((k_ >> 3) & 3);              \
        *(short8v*)&AXT[(kk_*64 + ln_)*8] = *(short8v*)tB_;                    \
    }

    // ---- level-0 gather (roots/slots: written by prep, always clean) ----
    if (tid < 256) {
        const float* src; bool pad;
        RESOLVE_SRC(0, src, pad);
        unsigned long long u0[8];
        if (!pad) {
            LOAD8P(src, u0);
            bool ok; VERIFY(u0, ok);
            while (!ok) { __builtin_amdgcn_s_sleep(1); LOAD8(src, u0); VERIFY(u0, ok); }
        } else {
            #pragma unroll
            for (int q = 0; q < 8; q++) u0[q] = 0ull;
        }
        WRITE_FRAGS_U(axFA, u0);
    }
    __syncthreads();

    unsigned short* axc = axFA;
    unsigned short* axn = axFB;

    for (int l = 0; l < LL; l++) {
        bool havN = (l + 1 < LL);

        // ---- phase A: issue PLAIN loads for level l+1 parents ----
        const float* srcN = nullptr; bool padN = true; bool ok = true;
        unsigned long long u[8];
        #pragma unroll
        for (int q = 0; q < 8; q++) u[q] = 0ull;
        if (havN && tid < 256) {
            RESOLVE_SRC(l+1, srcN, padN);
            if (!padN) { LOAD8P(srcN, u); ok = false; }
        }
        __builtin_amdgcn_sched_barrier(0);   // pin: loads issued before compute

        int e = ech[l];
        if (e >= 0) {
            // ---- layer 1: H = GELU(X @ W1 + b1), split 4+4 accumulator chains ----
            f32x4 z4 = (f32x4){0.f, 0.f, 0.f, 0.f};
            f32x4 acc0 = (f32x4){b1v0, b1v0, b1v0, b1v0}, acc0b = z4;
            f32x4 acc1 = (f32x4){b1v1, b1v1, b1v1, b1v1}, acc1b = z4;
            {
                const short8v* Ab = (const short8v*)axc;
                #pragma unroll
                for (int kk = 0; kk < 4; kk++) {
                    short8v a = Ab[kk*64 + lq];
                    acc0 = __builtin_amdgcn_mfma_f32_16x16x32_bf16(a, w1r0[kk], acc0, 0, 0, 0);
                    acc1 = __builtin_amdgcn_mfma_f32_16x16x32_bf16(a, w1r1[kk], acc1, 0, 0, 0);
                }
                #pragma unroll
                for (int kk = 4; kk < 8; kk++) {
                    short8v a = Ab[kk*64 + lq];
                    acc0b = __builtin_amdgcn_mfma_f32_16x16x32_bf16(a, w1r0[kk], acc0b, 0, 0, 0);
                    acc1b = __builtin_amdgcn_mfma_f32_16x16x32_bf16(a, w1r1[kk], acc1b, 0, 0, 0);
                }
            }
            acc0 += acc0b;
            acc1 += acc1b;
            // ---- check A: data arrived? if sentinel, sc1 reissue (hidden) ----
            if (havN && tid < 256 && !padN && !ok) {
                VERIFY(u, ok);
                if (!ok) LOAD8(srcN, u);
            }
            __builtin_amdgcn_sched_barrier(0);

            // GELU + scatter H into A-frag LDS (nt = 2w+c, c in {0,1})
            #pragma unroll
            for (int c = 0; c < 2; c++) {
                int nh = (2*w + c)*16 + (lq & 15);
                int kk2 = nh >> 5;
                int jj  = nh & 7;
                int lhi = 16*((nh >> 3) & 3);
                #pragma unroll
                for (int r = 0; r < 4; r++) {
                    int m = (lq >> 4)*4 + r;
                    float h = (c == 0) ? acc0[r] : acc1[r];
                    hxF[(kk2*64 + (m + lhi))*8 + jj] = f2bf(gelu_f(h));
                }
            }
            __syncthreads();

            // ---- layer 2: OUT = H @ W2 + b2, split 4+4 chains ----
            f32x4 acc2 = (f32x4){b2v, b2v, b2v, b2v}, acc2b = z4;
            {
                const short8v* Hb = (const short8v*)hxF;
                #pragma unroll
                for (int kk = 0; kk < 4; kk++) {
                    short8v a = Hb[kk*64 + lq];
                    acc2 = __builtin_amdgcn_mfma_f32_16x16x32_bf16(a, w2r[kk], acc2, 0, 0, 0);
                }
                #pragma unroll
                for (int kk = 4; kk < 8; kk++) {
                    short8v a = Hb[kk*64 + lq];
                    acc2b = __builtin_amdgcn_mfma_f32_16x16x32_bf16(a, w2r[kk], acc2b, 0, 0, 0);
                }
            }
            acc2 += acc2b;
            // result rows: sc1 write-through; fire-and-forget (no drain, no flag)
            int baserow = RR + l*MM;
            int n = w*16 + (lq & 15);
            #pragma unroll
            for (int r = 0; r < 4; r++) {
                int m = (lq >> 4)*4 + r;
                int node = descs[l][m].x;
                if (node >= 0)
                    __hip_atomic_store(&buf[(size_t)(baserow + node)*DD + n], acc2[r],
                                       __ATOMIC_RELAXED, __HIP_MEMORY_SCOPE_AGENT);
            }
            // ---- check B: rides the store window ----
            if (havN && tid < 256 && !padN && !ok) {
                VERIFY(u, ok);
                if (!ok) LOAD8(srcN, u);
            }
        }

        // ---- phase B: spin (sc1) only on genuine still-pending parents ----
        if (havN && tid < 256) {
            if (!padN) {
                while (!ok) {
                    VERIFY(u, ok);
                    if (!ok) { __builtin_amdgcn_s_sleep(1); LOAD8(srcN, u); }
                }
            }
            WRITE_FRAGS_U(axn, u);
        }

        __syncthreads();
        unsigned short* t2 = axc; axc = axn; axn = t2;
    }
}

extern "C" void kernel_launch(void* const* d_in, const int* in_sizes, int n_in,
                              void* d_out, int out_size, void* d_ws, size_t ws_size,
                              hipStream_t stream) {
    const float* root  = (const float*)d_in[0];   // (1024, 128)
    const float* W1    = (const float*)d_in[1];   // (5, 256, 256)
    const float* b1    = (const float*)d_in[2];   // (5, 256)
    const float* W2    = (const float*)d_in[3];   // (5, 256, 128)
    const float* b2    = (const float*)d_in[4];   // (5, 128)
    const float* slots = (const float*)d_in[5];   // (256, 128)
    const int*   par   = (const int*)d_in[6];     // (131072, 2)
    const int*   typ   = (const int*)d_in[7];     // (131072,)
    float* out = (float*)d_out;                   // (132096, 128)

    unsigned short* W1F   = (unsigned short*)d_ws;          // 327680 shorts
    unsigned short* W2F   = W1F + 5*16*8*64*8;              // 163840 shorts
    unsigned short* order = W2F + 5*8*8*64*8;               // 64*2528 shorts

    // single fused prep dispatch (order, weights, roots, SENTINEL fill)
    prep_all<<<LL + 240 + 32 + 4096, 256, 0, stream>>>(root, W1, W2, typ, par, out,
                                                       W1F, W2F, order);

    // persistent dataflow sweep (co-residency guaranteed by cooperative launch)
    void* args[] = { (void*)&W1F, (void*)&W2F, (void*)&b1, (void*)&b2,
                     (void*)&slots, (void*)&par, (void*)&typ, (void*)&order,
                     (void*)&out };
    hipLaunchCooperativeKernel((const void*)persist_mfma, dim3(CH), dim3(512),
                               args, 0, stream);
}